// Round 6
// baseline (459.602 us; speedup 1.0000x reference)
//
#include <hip/hip_runtime.h>
#include <stdint.h>

#define NTOK 16384
#define DIM 2048
#define HIDDEN 1408
#define NEXP 8
#define NPRIME 2816   // 2*HIDDEN, 32-col interleaved w1/w3

typedef short short8 __attribute__((ext_vector_type(8)));
typedef float f32x16 __attribute__((ext_vector_type(16)));
typedef unsigned short u16;

// round-to-nearest-even fp32 -> bf16 (inputs finite; no NaN handling needed)
__device__ __forceinline__ u16 f2bf(float f) {
    uint32_t u = __float_as_uint(f);
    return (u16)((u + 0x7fffu + ((u >> 16) & 1u)) >> 16);
}

// async global->LDS, 16B per lane. LDS dest is wave-uniform base + lane*16.
__device__ __forceinline__ void gload16(const u16* g, u16* l) {
    __builtin_amdgcn_global_load_lds(
        (const __attribute__((address_space(1))) void*)g,
        (__attribute__((address_space(3))) void*)l,
        16, 0, 0);
}

// ---------------------------------------------------------------- cvt f32->bf16
__global__ __launch_bounds__(256) void cvt_kernel(const float* __restrict__ src,
                                                  u16* __restrict__ dst, long n) {
    long i0 = ((long)blockIdx.x * 256 + threadIdx.x) * 8;
    long stride = (long)gridDim.x * 256 * 8;
    for (long i = i0; i < n; i += stride) {
        float4 a = *(const float4*)(src + i);
        float4 b = *(const float4*)(src + i + 4);
        uint4 o;
        o.x = (uint32_t)f2bf(a.x) | ((uint32_t)f2bf(a.y) << 16);
        o.y = (uint32_t)f2bf(a.z) | ((uint32_t)f2bf(a.w) << 16);
        o.z = (uint32_t)f2bf(b.x) | ((uint32_t)f2bf(b.y) << 16);
        o.w = (uint32_t)f2bf(b.z) | ((uint32_t)f2bf(b.w) << 16);
        *(uint4*)(dst + i) = o;
    }
}

// ---------------------------------------------------------------- cvt+interleave w1/w3
// 32-col granularity: dst row n': p=n'>>6, s=(n'>>5)&1, c=n'&31; hidden col = p*32+c
// source = (s ? w3 : w1)[e][hcol][:]. One block per (e,n') row; 256 thr x 8 elems.
__global__ __launch_bounds__(256) void cvt13_kernel(const float* __restrict__ w1,
                                                    const float* __restrict__ w3,
                                                    u16* __restrict__ dst) {
    const int r  = blockIdx.x;            // 0 .. 8*2816-1
    const int e  = r / NPRIME;
    const int np = r - e * NPRIME;
    const int p  = np >> 6;
    const int s  = (np >> 5) & 1;
    const int c  = np & 31;
    const int hcol = p * 32 + c;
    const float* src = (s ? w3 : w1) + ((size_t)e * HIDDEN + hcol) * DIM;
    u16* d = dst + (size_t)r * DIM;
    const int i = threadIdx.x * 8;
    float4 a = *(const float4*)(src + i);
    float4 b = *(const float4*)(src + i + 4);
    uint4 o;
    o.x = (uint32_t)f2bf(a.x) | ((uint32_t)f2bf(a.y) << 16);
    o.y = (uint32_t)f2bf(a.z) | ((uint32_t)f2bf(a.w) << 16);
    o.z = (uint32_t)f2bf(b.x) | ((uint32_t)f2bf(b.y) << 16);
    o.w = (uint32_t)f2bf(b.z) | ((uint32_t)f2bf(b.w) << 16);
    *(uint4*)(d + i) = o;
}

// ---------------------------------------------------------------- FFN1 (X @ B'^T, fused SwiGLU)
// m97 structure, 32x32x16 MFMA: 128x128 tile, BK=64, 256 thr = 4 waves (2x2),
// wave 64x64 = 2x2 frags of 32x32. j=0 frag = c1, j=1 = c3 (same 32 hidden cols).
__global__ __launch_bounds__(256) void ffn1_kernel(
    const u16* __restrict__ xb, const u16* __restrict__ wb13,
    const int* __restrict__ ntpe, u16* __restrict__ hb)
{
    __shared__ u16 As[128 * 64];
    __shared__ u16 Bs[128 * 64];

    const int mt = blockIdx.x;   // 0..15 token tiles
    const int nt = blockIdx.y;   // 0..21 n' tiles
    const int e  = blockIdx.z;

    int base = 0;
    #pragma unroll
    for (int i = 0; i < NEXP; ++i) base += (i < e) ? ntpe[i] : 0;
    const int cnt = ntpe[e];
    if (mt * 128 >= cnt) return;

    const int tid  = threadIdx.x;
    const int lane = tid & 63;
    const int wid  = tid >> 6;   // 0..3
    const int wr   = wid >> 1;   // 0..1 -> 64-row group
    const int wc   = wid & 1;    // 0..1 -> 64-col group
    const int l5   = lane >> 5;  // half-wave
    const int lr   = lane & 31;

    const size_t m0 = (size_t)base + (size_t)mt * 128;
    const u16* Ag = xb   + m0 * DIM;
    const u16* Bg = wb13 + ((size_t)e * NPRIME + nt * 128) * DIM;

    f32x16 acc[2][2] = {};

    for (int k0 = 0; k0 < DIM; k0 += 64) {
        if (k0) __syncthreads();
        #pragma unroll
        for (int it = 0; it < 4; ++it) {
            int c   = it * 256 + tid;            // 0..1023
            int row = c >> 3;                    // 0..127
            int col = ((c & 7) ^ (row & 7)) * 8; // swizzled 8-elem chunk
            size_t go = (size_t)row * DIM + k0 + col;
            gload16(Ag + go, &As[c * 8]);
            gload16(Bg + go, &Bs[c * 8]);
        }
        __syncthreads();

        #pragma unroll
        for (int ks = 0; ks < 4; ++ks) {
            const int cj = ks * 2 + l5;          // 16B chunk along K
            short8 af[2], bf[2];
            #pragma unroll
            for (int i = 0; i < 2; ++i) {
                int ar = wr * 64 + i * 32 + lr;
                af[i] = *(const short8*)&As[ar * 64 + ((cj ^ (ar & 7)) << 3)];
                int br = wc * 64 + i * 32 + lr;
                bf[i] = *(const short8*)&Bs[br * 64 + ((cj ^ (br & 7)) << 3)];
            }
            #pragma unroll
            for (int i = 0; i < 2; ++i)
                #pragma unroll
                for (int j = 0; j < 2; ++j)
                    acc[i][j] = __builtin_amdgcn_mfma_f32_32x32x16_bf16(af[i], bf[j], acc[i][j], 0, 0, 0);
        }
    }

    // epilogue: h = silu(c1)*c3.
    // C/D map (32x32): col=lane&31, row=(r&3)+8*(r>>2)+4*(lane>>5)
    #pragma unroll
    for (int i = 0; i < 2; ++i) {
        const int hcol = (nt * 2 + wc) * 32 + lr;
        #pragma unroll
        for (int r = 0; r < 16; ++r) {
            int mrow = mt * 128 + wr * 64 + i * 32 + (r & 3) + 8 * (r >> 2) + 4 * l5;
            if (mrow < cnt) {
                float v1 = acc[i][0][r];
                float v3 = acc[i][1][r];
                float h = (v1 / (1.f + __expf(-v1))) * v3;
                hb[((size_t)base + mrow) * HIDDEN + hcol] = f2bf(h);
            }
        }
    }
}

// ---------------------------------------------------------------- FFN2 (h @ W2^T -> out fp32)
__global__ __launch_bounds__(256) void ffn2_kernel(
    const u16* __restrict__ hb, const u16* __restrict__ w2b,
    const int* __restrict__ ntpe, float* __restrict__ out)
{
    __shared__ u16 As[128 * 64];
    __shared__ u16 Bs[128 * 64];

    const int mt = blockIdx.x;   // 0..15 token tiles
    const int nt = blockIdx.y;   // 0..15 dim tiles
    const int e  = blockIdx.z;

    int base = 0;
    #pragma unroll
    for (int i = 0; i < NEXP; ++i) base += (i < e) ? ntpe[i] : 0;
    const int cnt = ntpe[e];
    if (mt * 128 >= cnt) return;

    const int tid  = threadIdx.x;
    const int lane = tid & 63;
    const int wid  = tid >> 6;   // 0..3
    const int wr   = wid >> 1;   // 0..1 -> 64-row group
    const int wc   = wid & 1;    // 0..1 -> 64-col group
    const int l5   = lane >> 5;
    const int lr   = lane & 31;

    const size_t m0 = (size_t)base + (size_t)mt * 128;
    const int    n0 = nt * 128;
    const u16* Ag = hb  + m0 * HIDDEN;
    const u16* Bg = w2b + ((size_t)e * DIM + n0) * HIDDEN;

    f32x16 acc[2][2] = {};

    for (int k0 = 0; k0 < HIDDEN; k0 += 64) {
        if (k0) __syncthreads();
        #pragma unroll
        for (int it = 0; it < 4; ++it) {
            int c   = it * 256 + tid;
            int row = c >> 3;
            int col = ((c & 7) ^ (row & 7)) * 8;
            size_t go = (size_t)row * HIDDEN + k0 + col;
            gload16(Ag + go, &As[c * 8]);
            gload16(Bg + go, &Bs[c * 8]);
        }
        __syncthreads();

        #pragma unroll
        for (int ks = 0; ks < 4; ++ks) {
            const int cj = ks * 2 + l5;
            short8 af[2], bf[2];
            #pragma unroll
            for (int i = 0; i < 2; ++i) {
                int ar = wr * 64 + i * 32 + lr;
                af[i] = *(const short8*)&As[ar * 64 + ((cj ^ (ar & 7)) << 3)];
                int br = wc * 64 + i * 32 + lr;
                bf[i] = *(const short8*)&Bs[br * 64 + ((cj ^ (br & 7)) << 3)];
            }
            #pragma unroll
            for (int i = 0; i < 2; ++i)
                #pragma unroll
                for (int j = 0; j < 2; ++j)
                    acc[i][j] = __builtin_amdgcn_mfma_f32_32x32x16_bf16(af[i], bf[j], acc[i][j], 0, 0, 0);
        }
    }

    #pragma unroll
    for (int i = 0; i < 2; ++i)
        #pragma unroll
        for (int j = 0; j < 2; ++j)
            #pragma unroll
            for (int r = 0; r < 16; ++r) {
                int mrow = mt * 128 + wr * 64 + i * 32 + (r & 3) + 8 * (r >> 2) + 4 * l5;
                if (mrow < cnt)
                    out[((size_t)base + mrow) * DIM + (n0 + wc * 64 + j * 32 + lr)] = acc[i][j][r];
            }
}

// ---------------------------------------------------------------- launch
extern "C" void kernel_launch(void* const* d_in, const int* in_sizes, int n_in,
                              void* d_out, int out_size, void* d_ws, size_t ws_size,
                              hipStream_t stream) {
    const float* x  = (const float*)d_in[0];
    const float* w1 = (const float*)d_in[1];
    const float* w2 = (const float*)d_in[2];  // dict order: x, w1, w2, w3, ntpe
    const float* w3 = (const float*)d_in[3];
    const int* ntpe = (const int*)d_in[4];
    float* out = (float*)d_out;

    // ws layout (bf16): xb | wb13 (interleaved w1/w3) | w2b | hb
    u16* xb   = (u16*)d_ws;
    u16* wb13 = xb   + (size_t)NTOK * DIM;
    u16* w2b  = wb13 + (size_t)NEXP * NPRIME * DIM;
    u16* hb   = w2b  + (size_t)NEXP * DIM * HIDDEN;

    cvt_kernel<<<2048, 256, 0, stream>>>(w2, w2b, (long)NEXP * DIM * HIDDEN);
    cvt_kernel<<<2048, 256, 0, stream>>>(x,  xb,  (long)NTOK * DIM);
    cvt13_kernel<<<NEXP * NPRIME, 256, 0, stream>>>(w1, w3, wb13);

    ffn1_kernel<<<dim3(16, 22, NEXP), 256, 0, stream>>>(xb, wb13, ntpe, hb);
    ffn2_kernel<<<dim3(16, 16, NEXP), 256, 0, stream>>>(hb, w2b, ntpe, out);
}

// Round 7
// 428.793 us; speedup vs baseline: 1.0719x; 1.0719x over previous
//
#include <hip/hip_runtime.h>
#include <stdint.h>

#define NTOK 16384
#define DIM 2048
#define HIDDEN 1408
#define NEXP 8
#define NPRIME 2816   // 2*HIDDEN, 16-col interleaved w1/w3

typedef short short8 __attribute__((ext_vector_type(8)));
typedef float f32x4 __attribute__((ext_vector_type(4)));
typedef unsigned short u16;

// round-to-nearest-even fp32 -> bf16 (inputs finite; no NaN handling needed)
__device__ __forceinline__ u16 f2bf(float f) {
    uint32_t u = __float_as_uint(f);
    return (u16)((u + 0x7fffu + ((u >> 16) & 1u)) >> 16);
}

// async global->LDS, 16B per lane. LDS dest is wave-uniform base + lane*16.
__device__ __forceinline__ void gload16(const u16* g, u16* l) {
    __builtin_amdgcn_global_load_lds(
        (const __attribute__((address_space(1))) void*)g,
        (__attribute__((address_space(3))) void*)l,
        16, 0, 0);
}

// ---------------------------------------------------------------- cvt f32->bf16
__global__ __launch_bounds__(256) void cvt_kernel(const float* __restrict__ src,
                                                  u16* __restrict__ dst, long n) {
    long i0 = ((long)blockIdx.x * 256 + threadIdx.x) * 8;
    long stride = (long)gridDim.x * 256 * 8;
    for (long i = i0; i < n; i += stride) {
        float4 a = *(const float4*)(src + i);
        float4 b = *(const float4*)(src + i + 4);
        uint4 o;
        o.x = (uint32_t)f2bf(a.x) | ((uint32_t)f2bf(a.y) << 16);
        o.y = (uint32_t)f2bf(a.z) | ((uint32_t)f2bf(a.w) << 16);
        o.z = (uint32_t)f2bf(b.x) | ((uint32_t)f2bf(b.y) << 16);
        o.w = (uint32_t)f2bf(b.z) | ((uint32_t)f2bf(b.w) << 16);
        *(uint4*)(dst + i) = o;
    }
}

// ---------------------------------------------------------------- cvt+interleave w1/w3
// dst row n' (of 2816 per expert): p=n'>>5, s=(n'>>4)&1, c=n'&15; hidden col = p*16+c
// source = (s ? w3 : w1)[e][hcol][:]. One block per (e,n') row; 256 thr x 8 elems.
__global__ __launch_bounds__(256) void cvt13_kernel(const float* __restrict__ w1,
                                                    const float* __restrict__ w3,
                                                    u16* __restrict__ dst) {
    const int r  = blockIdx.x;            // 0 .. 8*2816-1
    const int e  = r / NPRIME;
    const int np = r - e * NPRIME;
    const int p  = np >> 5;
    const int s  = (np >> 4) & 1;
    const int c  = np & 15;
    const int hcol = p * 16 + c;
    const float* src = (s ? w3 : w1) + ((size_t)e * HIDDEN + hcol) * DIM;
    u16* d = dst + (size_t)r * DIM;
    const int i = threadIdx.x * 8;
    float4 a = *(const float4*)(src + i);
    float4 b = *(const float4*)(src + i + 4);
    uint4 o;
    o.x = (uint32_t)f2bf(a.x) | ((uint32_t)f2bf(a.y) << 16);
    o.y = (uint32_t)f2bf(a.z) | ((uint32_t)f2bf(a.w) << 16);
    o.z = (uint32_t)f2bf(b.x) | ((uint32_t)f2bf(b.y) << 16);
    o.w = (uint32_t)f2bf(b.z) | ((uint32_t)f2bf(b.w) << 16);
    *(uint4*)(d + i) = o;
}

// ---------------------------------------------------------------- FFN1 (X @ B'^T, fused SwiGLU)
// m97 structure: 128x128 tile, BK=64, 256 threads = 4 waves (2x2), wave 64x64.
// 5 blocks/CU (32KB LDS): inter-block overlap hides the staging drain (m114).
// Deliberately NO XCD swizzle (R4: −11 µs) and NO deep pipeline (R2/R3: −70/−90 µs).
__global__ __launch_bounds__(256) void ffn1_kernel(
    const u16* __restrict__ xb, const u16* __restrict__ wb13,
    const int* __restrict__ ntpe, u16* __restrict__ hb)
{
    __shared__ u16 As[128 * 64];
    __shared__ u16 Bs[128 * 64];

    const int mt = blockIdx.x;   // 0..15 token tiles
    const int nt = blockIdx.y;   // 0..21 n' tiles
    const int e  = blockIdx.z;

    int base = 0;
    #pragma unroll
    for (int i = 0; i < NEXP; ++i) base += (i < e) ? ntpe[i] : 0;
    const int cnt = ntpe[e];
    if (mt * 128 >= cnt) return;

    const int tid  = threadIdx.x;
    const int lane = tid & 63;
    const int wid  = tid >> 6;   // 0..3
    const int wr   = wid >> 1;   // 0..1 -> 64-row group
    const int wc   = wid & 1;    // 0..1 -> 64-col group
    const int lq   = lane >> 4;
    const int lm   = lane & 15;

    const size_t m0 = (size_t)base + (size_t)mt * 128;
    const u16* Ag = xb   + m0 * DIM;
    const u16* Bg = wb13 + ((size_t)e * NPRIME + nt * 128) * DIM;

    f32x4 acc[4][4] = {};

    for (int k0 = 0; k0 < DIM; k0 += 64) {
        if (k0) __syncthreads();
        #pragma unroll
        for (int it = 0; it < 4; ++it) {
            int c   = it * 256 + tid;            // 0..1023
            int row = c >> 3;                    // 0..127
            int col = ((c & 7) ^ (row & 7)) * 8; // swizzled 8-elem chunk
            size_t go = (size_t)row * DIM + k0 + col;
            gload16(Ag + go, &As[c * 8]);
            gload16(Bg + go, &Bs[c * 8]);
        }
        __syncthreads();

        #pragma unroll
        for (int kk = 0; kk < 2; ++kk) {
            const int gc = kk * 4 + lq;
            short8 af[4], bf[4];
            #pragma unroll
            for (int i = 0; i < 4; ++i) {
                int ar = wr * 64 + i * 16 + lm;
                af[i] = *(const short8*)&As[ar * 64 + ((gc ^ (ar & 7)) << 3)];
                int br = wc * 64 + i * 16 + lm;
                bf[i] = *(const short8*)&Bs[br * 64 + ((gc ^ (br & 7)) << 3)];
            }
            #pragma unroll
            for (int i = 0; i < 4; ++i)
                #pragma unroll
                for (int j = 0; j < 4; ++j)
                    acc[i][j] = __builtin_amdgcn_mfma_f32_16x16x32_bf16(af[i], bf[j], acc[i][j], 0, 0, 0);
        }
    }

    // epilogue: frag j even = c1, j odd = c3 (same 16 hidden cols).
    // h = silu(c1)*c3.  C/D map: col=lane&15, row=(lane>>4)*4+r.
    #pragma unroll
    for (int i = 0; i < 4; ++i)
        #pragma unroll
        for (int jp = 0; jp < 4; jp += 2) {
            const int p = nt * 4 + wc * 2 + (jp >> 1);   // 16-col hidden group
            #pragma unroll
            for (int r = 0; r < 4; ++r) {
                int mrow = mt * 128 + wr * 64 + i * 16 + lq * 4 + r;
                if (mrow < cnt) {
                    float v1 = acc[i][jp][r];
                    float v3 = acc[i][jp + 1][r];
                    float h = (v1 / (1.f + __expf(-v1))) * v3;
                    hb[((size_t)base + mrow) * HIDDEN + p * 16 + lm] = f2bf(h);
                }
            }
        }
}

// ---------------------------------------------------------------- FFN2 (h @ W2^T -> out fp32)
// m97 structure: 128x128 tile, BK=64, 256 threads = 4 waves (2x2), wave 64x64.
__global__ __launch_bounds__(256) void ffn2_kernel(
    const u16* __restrict__ hb, const u16* __restrict__ w2b,
    const int* __restrict__ ntpe, float* __restrict__ out)
{
    __shared__ u16 As[128 * 64];
    __shared__ u16 Bs[128 * 64];

    const int mt = blockIdx.x;   // 0..15 token tiles
    const int nt = blockIdx.y;   // 0..15 dim tiles
    const int e  = blockIdx.z;

    int base = 0;
    #pragma unroll
    for (int i = 0; i < NEXP; ++i) base += (i < e) ? ntpe[i] : 0;
    const int cnt = ntpe[e];
    if (mt * 128 >= cnt) return;

    const int tid  = threadIdx.x;
    const int lane = tid & 63;
    const int wid  = tid >> 6;   // 0..3
    const int wr   = wid >> 1;   // 0..1 -> 64-row group
    const int wc   = wid & 1;    // 0..1 -> 64-col group
    const int lq   = lane >> 4;
    const int lm   = lane & 15;

    const size_t m0 = (size_t)base + (size_t)mt * 128;
    const int    n0 = nt * 128;
    const u16* Ag = hb  + m0 * HIDDEN;
    const u16* Bg = w2b + ((size_t)e * DIM + n0) * HIDDEN;

    f32x4 acc[4][4] = {};

    for (int k0 = 0; k0 < HIDDEN; k0 += 64) {
        if (k0) __syncthreads();
        #pragma unroll
        for (int it = 0; it < 4; ++it) {
            int c   = it * 256 + tid;
            int row = c >> 3;
            int col = ((c & 7) ^ (row & 7)) * 8;
            size_t go = (size_t)row * HIDDEN + k0 + col;
            gload16(Ag + go, &As[c * 8]);
            gload16(Bg + go, &Bs[c * 8]);
        }
        __syncthreads();

        #pragma unroll
        for (int kk = 0; kk < 2; ++kk) {
            const int gc = kk * 4 + lq;
            short8 af[4], bf[4];
            #pragma unroll
            for (int i = 0; i < 4; ++i) {
                int ar = wr * 64 + i * 16 + lm;
                af[i] = *(const short8*)&As[ar * 64 + ((gc ^ (ar & 7)) << 3)];
                int br = wc * 64 + i * 16 + lm;
                bf[i] = *(const short8*)&Bs[br * 64 + ((gc ^ (br & 7)) << 3)];
            }
            #pragma unroll
            for (int i = 0; i < 4; ++i)
                #pragma unroll
                for (int j = 0; j < 4; ++j)
                    acc[i][j] = __builtin_amdgcn_mfma_f32_16x16x32_bf16(af[i], bf[j], acc[i][j], 0, 0, 0);
        }
    }

    #pragma unroll
    for (int i = 0; i < 4; ++i)
        #pragma unroll
        for (int j = 0; j < 4; ++j)
            #pragma unroll
            for (int r = 0; r < 4; ++r) {
                int mrow = mt * 128 + wr * 64 + i * 16 + lq * 4 + r;
                if (mrow < cnt)
                    out[((size_t)base + mrow) * DIM + (n0 + wc * 64 + j * 16 + lm)] = acc[i][j][r];
            }
}

// ---------------------------------------------------------------- launch
extern "C" void kernel_launch(void* const* d_in, const int* in_sizes, int n_in,
                              void* d_out, int out_size, void* d_ws, size_t ws_size,
                              hipStream_t stream) {
    const float* x  = (const float*)d_in[0];
    const float* w1 = (const float*)d_in[1];
    const float* w2 = (const float*)d_in[2];  // dict order: x, w1, w2, w3, ntpe
    const float* w3 = (const float*)d_in[3];
    const int* ntpe = (const int*)d_in[4];
    float* out = (float*)d_out;

    // ws layout (bf16): xb | wb13 (interleaved w1/w3) | w2b | hb
    u16* xb   = (u16*)d_ws;
    u16* wb13 = xb   + (size_t)NTOK * DIM;
    u16* w2b  = wb13 + (size_t)NEXP * NPRIME * DIM;
    u16* hb   = w2b  + (size_t)NEXP * DIM * HIDDEN;

    // order: w2 first, then x, then w13 -> ffn1's inputs are most L3-warm
    cvt_kernel<<<2048, 256, 0, stream>>>(w2, w2b, (long)NEXP * DIM * HIDDEN);
    cvt_kernel<<<2048, 256, 0, stream>>>(x,  xb,  (long)NTOK * DIM);
    cvt13_kernel<<<NEXP * NPRIME, 256, 0, stream>>>(w1, w3, wb13);

    ffn1_kernel<<<dim3(16, 22, NEXP), 256, 0, stream>>>(xb, wb13, ntpe, hb);
    ffn2_kernel<<<dim3(16, 16, NEXP), 256, 0, stream>>>(hb, w2b, ntpe, out);
}